// Round 4
// baseline (159.997 us; speedup 1.0000x reference)
//
#include <hip/hip_runtime.h>
#include <hip/hip_bf16.h>
#include <math.h>

// NUM_MAPS=512, ZG=512, HID=96, SEQ=8, H1=3, H2=16, NPROC=8. fp32 in/out.
// R3 post-mortem: timed window ~70us harness overhead (268MB ws poison fill =
// 40.6us @82% HBM peak + input restores); k1+k2 ~45-50us controllable.
// R4: (a) k2 primes ALL its weights (345KB/CU) into L2 at kernel entry with
// one concurrent load burst (dummy-accumulate, kept by impossible branch);
// phases then hit L2 (~200cyc) instead of cold HBM (~900cyc).
// (b) k1 splits dots 8-way (64 loads/thread, fully unrolled -> 1-2 latency
// rounds instead of 4).

#define WS_ALPHA 0
#define WS_Q     512
#define WS_QKV   608

// ---------------------------------------------------------------------------
// K1 grid (595 blocks x 256):
//  blk 0..575   : QKV1 = K @ W{q,k,v}1. 72 blk/proc, 32 outputs/blk,
//                 8 k-splits (tid>>5), 64 loads/thread, full unroll.
//  blk 576..591 : alpha. 32 outputs/blk, 8 k-splits.
//  blk 592..594 : q.     32 outputs/blk, 8 k-splits.
// ---------------------------------------------------------------------------
__global__ __launch_bounds__(256) void k1_qkv_alpha_q(
    const float* __restrict__ x, const float* __restrict__ Wa,
    const float* __restrict__ ba, const float* __restrict__ Wqr,
    const float* __restrict__ bqr, const float* __restrict__ P,
    const float* __restrict__ Wq1, const float* __restrict__ Wk1,
    const float* __restrict__ Wv1, float* __restrict__ ws)
{
    __shared__ float sK[8 * 512];   // K tile (s-major) or x vector
    __shared__ float sp[256];       // partial sums
    const int blk = blockIdx.x, tid = threadIdx.x;

    if (blk < 576) {
        const int proc = blk / 72, c = blk % 72;
        // stage K[s][m] = P[proc,m,s] via float4 (1024 float4 = 4/thread)
        const float4* P4 = (const float4*)(P + proc * 4096);
        for (int i = tid; i < 1024; i += 256) {
            float4 v = P4[i];
            const int m = i >> 1, off = (i & 1) * 4;
            sK[(off + 0) * 512 + m] = v.x;
            sK[(off + 1) * 512 + m] = v.y;
            sK[(off + 2) * 512 + m] = v.z;
            sK[(off + 3) * 512 + m] = v.w;
        }
        __syncthreads();
        const int rl = tid & 31, sp8 = tid >> 5;
        const int r = c * 32 + rl;                 // 0..2303 within proc
        const int mat = r / 768, r2 = r % 768;
        const int s = r2 / 96, h = r2 % 96;
        const float* W = (mat == 0 ? Wq1 : (mat == 1 ? Wk1 : Wv1))
                         + proc * 49152 + (sp8 * 64) * 96 + h;
        const float* Ks = sK + s * 512 + sp8 * 64;
        float acc = 0.f;
        #pragma unroll
        for (int m2 = 0; m2 < 64; ++m2) acc += Ks[m2] * W[m2 * 96];
        sp[tid] = acc;
        __syncthreads();
        if (sp8 == 0) {
            float a = 0.f;
            #pragma unroll
            for (int j = 0; j < 8; ++j) a += sp[rl + 32 * j];
            ws[WS_QKV + proc * 2304 + r] = a;
        }
    } else if (blk < 592) {
        for (int k = tid; k < 512; k += 256) sK[k] = x[k];
        __syncthreads();
        const int ml = tid & 31, sp8 = tid >> 5;
        const int m = (blk - 576) * 32 + ml;
        const float* W = Wa + (sp8 * 64) * 512 + m;
        const float* xq = sK + sp8 * 64;
        float acc = 0.f;
        #pragma unroll
        for (int k = 0; k < 64; ++k) acc += xq[k] * W[k * 512];
        sp[tid] = acc;
        __syncthreads();
        if (sp8 == 0) {
            float a = ba[m];
            #pragma unroll
            for (int j = 0; j < 8; ++j) a += sp[ml + 32 * j];
            ws[WS_ALPHA + m] = 1.f / (1.f + __expf(-a));
        }
    } else {
        for (int k = tid; k < 512; k += 256) sK[k] = x[k];
        __syncthreads();
        const int hl = tid & 31, sp8 = tid >> 5;
        const int h = (blk - 592) * 32 + hl;       // 3*32 = 96, no guard needed
        const float* W = Wqr + (sp8 * 64) * 96 + h;
        const float* xq = sK + sp8 * 64;
        float acc = 0.f;
        #pragma unroll
        for (int k = 0; k < 64; ++k) acc += xq[k] * W[k * 96];
        sp[tid] = acc;
        __syncthreads();
        if (sp8 == 0) {
            float a = bqr[h];
            #pragma unroll
            for (int j = 0; j < 8; ++j) a += sp[hl + 32 * j];
            ws[WS_Q + h] = fmaxf(a, 0.f);
        }
    }
}

// ---------------------------------------------------------------------------
// K2: one block per processor. Entry: prime ALL weights into this CU's L2
// with one concurrent burst. Then attn1 -> fc1 -> K2/V2 -> attn2 -> fc2 ->
// Wo epilogue, all weight reads L2-hot.
// ---------------------------------------------------------------------------
__global__ __launch_bounds__(512) void k2_attn_out(
    const float* __restrict__ gate, const float* __restrict__ De,
    const float* __restrict__ regs, const float* __restrict__ fc1,
    const float* __restrict__ Wq2, const float* __restrict__ Wk2,
    const float* __restrict__ Wv2, const float* __restrict__ fc2,
    const float* __restrict__ Wo, float* __restrict__ ws,
    float* __restrict__ out)
{
    const int proc = blockIdx.x, tid = threadIdx.x;
    __shared__ float sQk[768], sKk[768], sVv[768], sH[768], sH2[768];
    __shared__ float sK2[768], sV2[768];
    __shared__ float sq[96], sQq[96], sO[96], sOf[96], sS[192], sg[8];
    const float rs = 0.10206207261596577f;  // 1/sqrt(96)

    // ---- L2 prime: issue every weight byte this block will need ----
    float dummy = 0.f;
    {
        const float2* f1p = (const float2*)(fc1 + proc * 9216) + tid * 9;
        const float2* q2p = (const float2*)(Wq2 + proc * 9216) + tid * 9;
        const float2* k2p = (const float2*)(Wk2 + proc * 9216) + tid * 9;
        const float2* v2p = (const float2*)(Wv2 + proc * 9216) + tid * 9;
        const float2* f2p = (const float2*)(fc2 + proc * 9216) + tid * 9;
        #pragma unroll
        for (int i = 0; i < 9; ++i) {
            float2 a = f1p[i], b = q2p[i], c = k2p[i], d = v2p[i], e = f2p[i];
            dummy += a.x + a.y + b.x + b.y + c.x + c.y + d.x + d.y + e.x + e.y;
        }
        const float4* wo4 = (const float4*)(Wo + proc * 49152) + tid * 24;
        #pragma unroll
        for (int i = 0; i < 24; ++i) {
            float4 v = wo4[i]; dummy += v.x + v.y + v.z + v.w;
        }
    }

    const float* qkv = ws + WS_QKV + proc * 2304;
    for (int i = tid; i < 768; i += 512) {
        sQk[i] = qkv[i]; sKk[i] = qkv[768 + i]; sVv[i] = qkv[1536 + i];
    }
    if (tid < 96) sq[tid] = ws[WS_Q + tid];
    if (tid < 8)  sg[tid] = gate[tid];
    __syncthreads();

    // attn1 logits: 3 heads x 8 q x 8 k
    if (tid < 192) {
        const int h0 = tid / 64, rem = tid % 64, si = rem / 8, sk = rem % 8;
        float acc = 0.f;
        #pragma unroll
        for (int d = 0; d < 32; ++d)
            acc += sQk[si * 96 + h0 * 32 + d] * sKk[sk * 96 + h0 * 32 + d];
        sS[tid] = acc * rs;
    }
    __syncthreads();

    // softmax + O + residual: 24 (head, si) rows
    if (tid < 24) {
        const int h0 = tid / 8, si = tid % 8;
        const float* row = sS + h0 * 64 + si * 8;
        float mx = row[0];
        #pragma unroll
        for (int k = 1; k < 8; ++k) mx = fmaxf(mx, row[k]);
        float e[8], sum = 0.f;
        #pragma unroll
        for (int k = 0; k < 8; ++k) { e[k] = __expf(row[k] - mx); sum += e[k]; }
        const float inv = 1.f / sum;
        #pragma unroll
        for (int d = 0; d < 32; ++d) {
            float o = 0.f;
            #pragma unroll
            for (int k = 0; k < 8; ++k) o += e[k] * sVv[k * 96 + h0 * 32 + d];
            const int idx = si * 96 + h0 * 32 + d;
            sH[idx] = sQk[idx] + o * inv;
        }
    }
    __syncthreads();

    // fc1: H2 = H + relu(H @ fc1)   (weights now L2-hot)
    for (int idx = tid; idx < 768; idx += 512) {
        const int s = idx / 96, j = idx % 96;
        const float* W = fc1 + proc * 9216 + j;
        const float* Hs = sH + s * 96;
        float acc = 0.f;
        #pragma unroll 32
        for (int i = 0; i < 96; ++i) acc += Hs[i] * W[i * 96];
        sH2[idx] = sH[idx] + fmaxf(acc, 0.f);
    }
    // Qq = q @ Wq2 (independent — same sync region)
    if (tid < 96) {
        const float* W = Wq2 + proc * 9216 + tid;
        float acc = 0.f;
        #pragma unroll 32
        for (int i = 0; i < 96; ++i) acc += sq[i] * W[i * 96];
        sQq[tid] = acc;
    }
    __syncthreads();

    // K2 = H2 @ Wk2, V2 = H2 @ Wv2
    for (int idx = tid; idx < 1536; idx += 512) {
        const int which = idx / 768, r = idx % 768;
        const int s = r / 96, j = r % 96;
        const float* W = (which ? Wv2 : Wk2) + proc * 9216 + j;
        const float* Hs = sH2 + s * 96;
        float acc = 0.f;
        #pragma unroll 32
        for (int i = 0; i < 96; ++i) acc += Hs[i] * W[i * 96];
        if (which) sV2[r] = acc; else sK2[r] = acc;
    }
    __syncthreads();

    // attn2: 16 heads, d=6, single query row
    if (tid < 16) {
        const int h0 = tid;
        float lg[8], mx = -1e30f;
        #pragma unroll
        for (int k = 0; k < 8; ++k) {
            float acc = 0.f;
            #pragma unroll
            for (int d = 0; d < 6; ++d)
                acc += sQq[h0 * 6 + d] * sK2[k * 96 + h0 * 6 + d];
            lg[k] = acc * rs; mx = fmaxf(mx, lg[k]);
        }
        float e[8], sum = 0.f;
        #pragma unroll
        for (int k = 0; k < 8; ++k) { e[k] = __expf(lg[k] - mx); sum += e[k]; }
        const float inv = 1.f / sum;
        #pragma unroll
        for (int d = 0; d < 6; ++d) {
            float o = 0.f;
            #pragma unroll
            for (int k = 0; k < 8; ++k) o += e[k] * sV2[k * 96 + h0 * 6 + d];
            sO[h0 * 6 + d] = sQq[h0 * 6 + d] + o * inv;
        }
    }
    __syncthreads();

    // fc2: Of = O + relu(O @ fc2)
    if (tid < 96) {
        const float* W = fc2 + proc * 9216 + tid;
        float acc = 0.f;
        #pragma unroll 32
        for (int i = 0; i < 96; ++i) acc += sO[i] * W[i * 96];
        sOf[tid] = sO[tid] + fmaxf(acc, 0.f);
    }
    __syncthreads();

    // Epilogue: trans[m] = Of @ Wo[:,m]; mix with de, alpha, regs, offs
    {
        const int m = tid;
        const float* W = Wo + proc * 49152 + m;
        float tr = 0.f;
        #pragma unroll 32
        for (int h = 0; h < 96; ++h) tr += sOf[h] * W[h * 512];
        const float4* Dp4 = (const float4*)(De + proc * 4096 + m * 8);
        const float4 d0 = Dp4[0], d1 = Dp4[1];
        const float de = d0.x * sg[0] + d0.y * sg[1] + d0.z * sg[2] + d0.w * sg[3]
                       + d1.x * sg[4] + d1.y * sg[5] + d1.z * sg[6] + d1.w * sg[7];
        const float a = ws[WS_ALPHA + m];
        const float mix = a * tr + (1.f - a) * de;
        const int pt = proc & 3;                 // gamma gets +1, beta not
        const float off = (pt == 0 || pt == 2) ? 1.f : 0.f;
        out[proc * 512 + m] = mix * regs[proc * 512 + m] + off;
    }

    // keep the prime loads alive; finite weights => never taken
    if (dummy != dummy) ws[WS_QKV + proc * 2304] = dummy;
}

extern "C" void kernel_launch(void* const* d_in, const int* in_sizes, int n_in,
                              void* d_out, int out_size, void* d_ws, size_t ws_size,
                              hipStream_t stream)
{
    const float* gate = (const float*)d_in[0];
    const float* x    = (const float*)d_in[1];
    const float* Wa   = (const float*)d_in[2];
    const float* ba   = (const float*)d_in[3];
    const float* Wqr  = (const float*)d_in[4];
    const float* bqr  = (const float*)d_in[5];
    const float* P    = (const float*)d_in[6];
    const float* De   = (const float*)d_in[7];
    const float* regs = (const float*)d_in[8];
    const float* Wq1  = (const float*)d_in[9];
    const float* Wk1  = (const float*)d_in[10];
    const float* Wv1  = (const float*)d_in[11];
    const float* fc1  = (const float*)d_in[12];
    const float* Wq2  = (const float*)d_in[13];
    const float* Wk2  = (const float*)d_in[14];
    const float* Wv2  = (const float*)d_in[15];
    const float* fc2  = (const float*)d_in[16];
    const float* Wo   = (const float*)d_in[17];
    float* ws = (float*)d_ws;

    hipLaunchKernelGGL(k1_qkv_alpha_q, dim3(595), dim3(256), 0, stream,
                       x, Wa, ba, Wqr, bqr, P, Wq1, Wk1, Wv1, ws);
    hipLaunchKernelGGL(k2_attn_out, dim3(8), dim3(512), 0, stream,
                       gate, De, regs, fc1, Wq2, Wk2, Wv2, fc2, Wo, ws,
                       (float*)d_out);
}

// Round 5
// 115.907 us; speedup vs baseline: 1.3804x; 1.3804x over previous
//
#include <hip/hip_runtime.h>
#include <hip/hip_bf16.h>
#include <math.h>

// NUM_MAPS=512, ZG=512, HID=96, SEQ=8, H1=3, H2=16, NPROC=8. fp32 in/out.
// R4 post-mortem: L2-prime REGRESSED k2 46->66us. Root cause: per-CU HBM BW
// ~24 GB/s (10 B/cyc/CU) — 8 blocks pulling 3MB = >=16us floor + prime
// doubled per-CU traffic (and was 72B-stride uncoalesced). Aggregate HBM
// need is only ~9MB (~1.4us chip-wide): the fix is MORE CUs per stage, not
// caching. R5: k2 -> 5 small kernels, each weight matrix spread over 24-64
// blocks (12-25 KB/block), LDS k-split reduction.

#define WS_ALPHA 0
#define WS_Q     512
#define WS_QKV   608      // 8*2304 -> ends 19040
#define WS_H     19040    // 8*768  -> 25184
#define WS_QQ    25184    // 8*96   -> 25952
#define WS_H2    25952    // 8*768  -> 32096
#define WS_K2    32096    // 8*768  -> 38240
#define WS_V2    38240    // 8*768  -> 44384
#define WS_OF    44384    // 8*96   -> 45152

// ---------------------------------------------------------------------------
// K1 (595 x 256): QKV1 (blk<576, 72/proc, 32 out/blk, 8-way k-split),
// alpha (576..591), q (592..594). Unchanged from R3 (verified).
// ---------------------------------------------------------------------------
__global__ __launch_bounds__(256) void k1_qkv_alpha_q(
    const float* __restrict__ x, const float* __restrict__ Wa,
    const float* __restrict__ ba, const float* __restrict__ Wqr,
    const float* __restrict__ bqr, const float* __restrict__ P,
    const float* __restrict__ Wq1, const float* __restrict__ Wk1,
    const float* __restrict__ Wv1, float* __restrict__ ws)
{
    __shared__ float sK[8 * 512];
    __shared__ float sp[256];
    const int blk = blockIdx.x, tid = threadIdx.x;

    if (blk < 576) {
        const int proc = blk / 72, c = blk % 72;
        const float4* P4 = (const float4*)(P + proc * 4096);
        for (int i = tid; i < 1024; i += 256) {
            float4 v = P4[i];
            const int m = i >> 1, off = (i & 1) * 4;
            sK[(off + 0) * 512 + m] = v.x;
            sK[(off + 1) * 512 + m] = v.y;
            sK[(off + 2) * 512 + m] = v.z;
            sK[(off + 3) * 512 + m] = v.w;
        }
        __syncthreads();
        const int rl = tid & 31, sp8 = tid >> 5;
        const int r = c * 32 + rl;
        const int mat = r / 768, r2 = r % 768;
        const int s = r2 / 96, h = r2 % 96;
        const float* W = (mat == 0 ? Wq1 : (mat == 1 ? Wk1 : Wv1))
                         + proc * 49152 + (sp8 * 64) * 96 + h;
        const float* Ks = sK + s * 512 + sp8 * 64;
        float acc = 0.f;
        #pragma unroll
        for (int m2 = 0; m2 < 64; ++m2) acc += Ks[m2] * W[m2 * 96];
        sp[tid] = acc;
        __syncthreads();
        if (sp8 == 0) {
            float a = 0.f;
            #pragma unroll
            for (int j = 0; j < 8; ++j) a += sp[rl + 32 * j];
            ws[WS_QKV + proc * 2304 + r] = a;
        }
    } else if (blk < 592) {
        for (int k = tid; k < 512; k += 256) sK[k] = x[k];
        __syncthreads();
        const int ml = tid & 31, sp8 = tid >> 5;
        const int m = (blk - 576) * 32 + ml;
        const float* W = Wa + (sp8 * 64) * 512 + m;
        const float* xq = sK + sp8 * 64;
        float acc = 0.f;
        #pragma unroll
        for (int k = 0; k < 64; ++k) acc += xq[k] * W[k * 512];
        sp[tid] = acc;
        __syncthreads();
        if (sp8 == 0) {
            float a = ba[m];
            #pragma unroll
            for (int j = 0; j < 8; ++j) a += sp[ml + 32 * j];
            ws[WS_ALPHA + m] = 1.f / (1.f + __expf(-a));
        }
    } else {
        for (int k = tid; k < 512; k += 256) sK[k] = x[k];
        __syncthreads();
        const int hl = tid & 31, sp8 = tid >> 5;
        const int h = (blk - 592) * 32 + hl;       // 3*32 = 96
        const float* W = Wqr + (sp8 * 64) * 96 + h;
        const float* xq = sK + sp8 * 64;
        float acc = 0.f;
        #pragma unroll
        for (int k = 0; k < 64; ++k) acc += xq[k] * W[k * 96];
        sp[tid] = acc;
        __syncthreads();
        if (sp8 == 0) {
            float a = bqr[h];
            #pragma unroll
            for (int j = 0; j < 8; ++j) a += sp[hl + 32 * j];
            ws[WS_Q + h] = fmaxf(a, 0.f);
        }
    }
}

// ---------------------------------------------------------------------------
// K2a (32 x 256): blk<8 -> attn1 per proc (no weights, reads QKV1);
// blk 8..31 -> Qq = q @ Wq2, (proc, third), 8-way k-split.
// ---------------------------------------------------------------------------
__global__ __launch_bounds__(256) void k2a_attn1_qq(
    const float* __restrict__ Wq2, float* __restrict__ ws)
{
    const int blk = blockIdx.x, tid = threadIdx.x;
    const float rs = 0.10206207261596577f;  // 1/sqrt(96)

    if (blk < 8) {
        const int proc = blk;
        __shared__ float sQk[768], sKk[768], sVv[768], sH[768], sS[192];
        const float* qkv = ws + WS_QKV + proc * 2304;
        for (int i = tid; i < 768; i += 256) {
            sQk[i] = qkv[i]; sKk[i] = qkv[768 + i]; sVv[i] = qkv[1536 + i];
        }
        __syncthreads();
        if (tid < 192) {   // 3 heads x 8 q x 8 k logits
            const int h0 = tid / 64, rem = tid % 64, si = rem / 8, sk = rem % 8;
            float acc = 0.f;
            #pragma unroll
            for (int d = 0; d < 32; ++d)
                acc += sQk[si * 96 + h0 * 32 + d] * sKk[sk * 96 + h0 * 32 + d];
            sS[tid] = acc * rs;
        }
        __syncthreads();
        if (tid < 24) {    // softmax + O + residual
            const int h0 = tid / 8, si = tid % 8;
            const float* row = sS + h0 * 64 + si * 8;
            float mx = row[0];
            #pragma unroll
            for (int k = 1; k < 8; ++k) mx = fmaxf(mx, row[k]);
            float e[8], sum = 0.f;
            #pragma unroll
            for (int k = 0; k < 8; ++k) { e[k] = __expf(row[k] - mx); sum += e[k]; }
            const float inv = 1.f / sum;
            #pragma unroll
            for (int d = 0; d < 32; ++d) {
                float o = 0.f;
                #pragma unroll
                for (int k = 0; k < 8; ++k) o += e[k] * sVv[k * 96 + h0 * 32 + d];
                const int idx = si * 96 + h0 * 32 + d;
                sH[idx] = sQk[idx] + o * inv;
            }
        }
        __syncthreads();
        float* Hout = ws + WS_H + proc * 768;
        for (int i = tid; i < 768; i += 256) Hout[i] = sH[i];
    } else {
        const int b2 = blk - 8, proc = b2 / 3, t = b2 % 3;
        __shared__ float sq[96], sp[256];
        if (tid < 96) sq[tid] = ws[WS_Q + tid];
        __syncthreads();
        const int jl = tid & 31, ks = tid >> 5;
        const int j = 32 * t + jl;
        const float* W = Wq2 + proc * 9216 + j;
        float acc = 0.f;
        #pragma unroll
        for (int i = 0; i < 12; ++i)
            acc += sq[12 * ks + i] * W[(12 * ks + i) * 96];
        sp[tid] = acc;
        __syncthreads();
        if (ks == 0) {
            float a = 0.f;
            #pragma unroll
            for (int u = 0; u < 8; ++u) a += sp[jl + 32 * u];
            ws[WS_QQ + proc * 96 + j] = a;
        }
    }
}

// ---------------------------------------------------------------------------
// K2b (24 x 256): H2 = H + relu(H @ fc1). (proc, third); thread = (s, jl).
// ---------------------------------------------------------------------------
__global__ __launch_bounds__(256) void k2b_fc1(
    const float* __restrict__ fc1, float* __restrict__ ws)
{
    const int b = blockIdx.x, proc = b / 3, t = b % 3, tid = threadIdx.x;
    __shared__ float sH[768];
    const float* Hin = ws + WS_H + proc * 768;
    for (int i = tid; i < 768; i += 256) sH[i] = Hin[i];
    __syncthreads();
    const int s = tid >> 5, jl = tid & 31, j = 32 * t + jl;
    const float* W = fc1 + proc * 9216 + j;
    const float* Hs = sH + s * 96;
    float acc = 0.f;
    #pragma unroll
    for (int i = 0; i < 96; ++i) acc += Hs[i] * W[i * 96];
    ws[WS_H2 + proc * 768 + s * 96 + j] = Hs[j] + fmaxf(acc, 0.f);
}

// ---------------------------------------------------------------------------
// K2c (48 x 256): K2 = H2@Wk2, V2 = H2@Wv2. (proc, mat, third).
// ---------------------------------------------------------------------------
__global__ __launch_bounds__(256) void k2c_kv2(
    const float* __restrict__ Wk2, const float* __restrict__ Wv2,
    float* __restrict__ ws)
{
    const int b = blockIdx.x, proc = b / 6, rem = b % 6;
    const int mat = rem / 3, t = rem % 3, tid = threadIdx.x;
    __shared__ float sH[768];
    const float* Hin = ws + WS_H2 + proc * 768;
    for (int i = tid; i < 768; i += 256) sH[i] = Hin[i];
    __syncthreads();
    const int s = tid >> 5, jl = tid & 31, j = 32 * t + jl;
    const float* W = (mat ? Wv2 : Wk2) + proc * 9216 + j;
    const float* Hs = sH + s * 96;
    float acc = 0.f;
    #pragma unroll
    for (int i = 0; i < 96; ++i) acc += Hs[i] * W[i * 96];
    ws[(mat ? WS_V2 : WS_K2) + proc * 768 + s * 96 + j] = acc;
}

// ---------------------------------------------------------------------------
// K2d (24 x 256): attn2 (redundant per block, no weights) + fc2 slice.
// (proc, third); fc2 8-way k-split.
// ---------------------------------------------------------------------------
__global__ __launch_bounds__(256) void k2d_attn2_fc2(
    const float* __restrict__ fc2, float* __restrict__ ws)
{
    const int b = blockIdx.x, proc = b / 3, t = b % 3, tid = threadIdx.x;
    __shared__ float sK2[768], sV2[768], sQq[96], sO[96], sp[256];
    const float rs = 0.10206207261596577f;
    for (int i = tid; i < 768; i += 256) {
        sK2[i] = ws[WS_K2 + proc * 768 + i];
        sV2[i] = ws[WS_V2 + proc * 768 + i];
    }
    if (tid < 96) sQq[tid] = ws[WS_QQ + proc * 96 + tid];
    __syncthreads();
    if (tid < 16) {        // attn2: 16 heads, d=6, 1 query row
        const int h0 = tid;
        float lg[8], mx = -1e30f;
        #pragma unroll
        for (int k = 0; k < 8; ++k) {
            float acc = 0.f;
            #pragma unroll
            for (int d = 0; d < 6; ++d)
                acc += sQq[h0 * 6 + d] * sK2[k * 96 + h0 * 6 + d];
            lg[k] = acc * rs; mx = fmaxf(mx, lg[k]);
        }
        float e[8], sum = 0.f;
        #pragma unroll
        for (int k = 0; k < 8; ++k) { e[k] = __expf(lg[k] - mx); sum += e[k]; }
        const float inv = 1.f / sum;
        #pragma unroll
        for (int d = 0; d < 6; ++d) {
            float o = 0.f;
            #pragma unroll
            for (int k = 0; k < 8; ++k) o += e[k] * sV2[k * 96 + h0 * 6 + d];
            sO[h0 * 6 + d] = sQq[h0 * 6 + d] + o * inv;
        }
    }
    __syncthreads();
    const int jl = tid & 31, ks = tid >> 5;
    const int j = 32 * t + jl;
    const float* W = fc2 + proc * 9216 + j;
    float acc = 0.f;
    #pragma unroll
    for (int i = 0; i < 12; ++i)
        acc += sO[12 * ks + i] * W[(12 * ks + i) * 96];
    sp[tid] = acc;
    __syncthreads();
    if (ks == 0) {
        float a = 0.f;
        #pragma unroll
        for (int u = 0; u < 8; ++u) a += sp[jl + 32 * u];
        ws[WS_OF + proc * 96 + j] = sO[j] + fmaxf(a, 0.f);
    }
}

// ---------------------------------------------------------------------------
// K2e (64 x 256): trans = Of @ Wo (+De*gate, alpha-mix, regs, offs).
// (proc, eighth): 64 maps/block, 4-way k-split.
// ---------------------------------------------------------------------------
__global__ __launch_bounds__(256) void k2e_out(
    const float* __restrict__ gate, const float* __restrict__ De,
    const float* __restrict__ regs, const float* __restrict__ Wo,
    const float* __restrict__ ws, float* __restrict__ out)
{
    const int b = blockIdx.x, proc = b >> 3, e = b & 7, tid = threadIdx.x;
    __shared__ float sOf[96], sg[8], sp[256];
    if (tid < 96) sOf[tid] = ws[WS_OF + proc * 96 + tid];
    else if (tid < 104) sg[tid - 96] = gate[tid - 96];
    __syncthreads();
    const int ml = tid & 63, ks = tid >> 6;
    const int m = 64 * e + ml;
    const float* W = Wo + proc * 49152 + m;
    float acc = 0.f;
    #pragma unroll
    for (int i = 0; i < 24; ++i)
        acc += sOf[24 * ks + i] * W[(24 * ks + i) * 512];
    sp[tid] = acc;
    __syncthreads();
    if (ks == 0) {
        const float tr = sp[ml] + sp[ml + 64] + sp[ml + 128] + sp[ml + 192];
        const float4* Dp4 = (const float4*)(De + proc * 4096 + m * 8);
        const float4 d0 = Dp4[0], d1 = Dp4[1];
        const float de = d0.x * sg[0] + d0.y * sg[1] + d0.z * sg[2] + d0.w * sg[3]
                       + d1.x * sg[4] + d1.y * sg[5] + d1.z * sg[6] + d1.w * sg[7];
        const float a = ws[WS_ALPHA + m];
        const float mix = a * tr + (1.f - a) * de;
        const int pt = proc & 3;                 // gamma gets +1, beta not
        const float off = (pt == 0 || pt == 2) ? 1.f : 0.f;
        out[proc * 512 + m] = mix * regs[proc * 512 + m] + off;
    }
}

extern "C" void kernel_launch(void* const* d_in, const int* in_sizes, int n_in,
                              void* d_out, int out_size, void* d_ws, size_t ws_size,
                              hipStream_t stream)
{
    const float* gate = (const float*)d_in[0];
    const float* x    = (const float*)d_in[1];
    const float* Wa   = (const float*)d_in[2];
    const float* ba   = (const float*)d_in[3];
    const float* Wqr  = (const float*)d_in[4];
    const float* bqr  = (const float*)d_in[5];
    const float* P    = (const float*)d_in[6];
    const float* De   = (const float*)d_in[7];
    const float* regs = (const float*)d_in[8];
    const float* Wq1  = (const float*)d_in[9];
    const float* Wk1  = (const float*)d_in[10];
    const float* Wv1  = (const float*)d_in[11];
    const float* fc1  = (const float*)d_in[12];
    const float* Wq2  = (const float*)d_in[13];
    const float* Wk2  = (const float*)d_in[14];
    const float* Wv2  = (const float*)d_in[15];
    const float* fc2  = (const float*)d_in[16];
    const float* Wo   = (const float*)d_in[17];
    float* ws = (float*)d_ws;

    hipLaunchKernelGGL(k1_qkv_alpha_q, dim3(595), dim3(256), 0, stream,
                       x, Wa, ba, Wqr, bqr, P, Wq1, Wk1, Wv1, ws);
    hipLaunchKernelGGL(k2a_attn1_qq, dim3(32), dim3(256), 0, stream, Wq2, ws);
    hipLaunchKernelGGL(k2b_fc1, dim3(24), dim3(256), 0, stream, fc1, ws);
    hipLaunchKernelGGL(k2c_kv2, dim3(48), dim3(256), 0, stream, Wk2, Wv2, ws);
    hipLaunchKernelGGL(k2d_attn2_fc2, dim3(24), dim3(256), 0, stream, fc2, ws);
    hipLaunchKernelGGL(k2e_out, dim3(64), dim3(256), 0, stream,
                       gate, De, regs, Wo, ws, (float*)d_out);
}

// Round 6
// 109.783 us; speedup vs baseline: 1.4574x; 1.0558x over previous
//
#include <hip/hip_runtime.h>
#include <hip/hip_bf16.h>
#include <math.h>

// NUM_MAPS=512, ZG=512, HID=96, SEQ=8, H1=3, H2=16, NPROC=8. fp32 in/out.
// R5 ledger: fixed harness ~84us (268MB poison fill 40.6us + ~20 restore
// dispatches); k1 ~10us; k2 chain ~22us REGARDLESS of 1-kernel (R3) or
// 6-kernel (R5) shape -> chain is launch-gap bound. R6: 3 kernels total via
// redundant recompute of cheap stages (attn1 per fc1-block, Qq/attn2/fc2 per
// Wo-block); k1 QKV computes all 8 s per W column (8x less traffic, 32KB/blk).

#define WS_ALPHA 0
#define WS_Q     512
#define WS_QKV   608      // 8*2304 -> ends 19040
#define WS_K2    19040    // 8*768  -> 25184
#define WS_V2    25184    // 8*768  -> 31328

// ---------------------------------------------------------------------------
// KA (179 x 256):
//  blk 0..143   : QKV1. (proc, mat, sixth): 16 h-cols x all 8 s per block.
//                 thread (hl 16, ks 16): 32 W loads, acc[8] over s, LDS skew
//                 sK[c + c/32] kills ks-stride bank conflicts.
//  blk 144..175 : alpha. 16 m/blk, 16-way k-split.
//  blk 176..178 : q. 32 h/blk, 8-way k-split.
// ---------------------------------------------------------------------------
__global__ __launch_bounds__(256) void kA_qkv_alpha_q(
    const float* __restrict__ x, const float* __restrict__ Wa,
    const float* __restrict__ ba, const float* __restrict__ Wqr,
    const float* __restrict__ bqr, const float* __restrict__ P,
    const float* __restrict__ Wq1, const float* __restrict__ Wk1,
    const float* __restrict__ Wv1, float* __restrict__ ws)
{
    __shared__ float sK[8 * 528];   // skewed K tile (c -> c + c/32), or x
    __shared__ float sp[2048];      // partial sums
    const int blk = blockIdx.x, tid = threadIdx.x;

    if (blk < 144) {
        const int proc = blk / 18, rem = blk % 18, mat = rem / 6, six = rem % 6;
        // stage K[s][c] = P[proc,c,s], column index skewed c -> c + (c>>5)
        const float4* P4 = (const float4*)(P + proc * 4096);
        for (int i = tid; i < 1024; i += 256) {
            float4 v = P4[i];
            const int c = i >> 1, off = (i & 1) * 4;
            const int cp = c + (c >> 5);
            sK[(off + 0) * 528 + cp] = v.x;
            sK[(off + 1) * 528 + cp] = v.y;
            sK[(off + 2) * 528 + cp] = v.z;
            sK[(off + 3) * 528 + cp] = v.w;
        }
        __syncthreads();
        const int hl = tid & 15, ks = tid >> 4;        // ks 0..15
        const int h = six * 16 + hl;
        const float* W = (mat == 0 ? Wq1 : (mat == 1 ? Wk1 : Wv1))
                         + proc * 49152 + (ks * 32) * 96 + h;
        // skewed column base for c = ks*32 + m2  ->  ks*33 + m2
        const float* Kb = sK + ks * 33;
        float acc[8] = {0.f,0.f,0.f,0.f,0.f,0.f,0.f,0.f};
        #pragma unroll
        for (int m2 = 0; m2 < 32; ++m2) {
            const float w = W[m2 * 96];
            const float* Kc = Kb + m2;
            #pragma unroll
            for (int s = 0; s < 8; ++s) acc[s] += Kc[s * 528] * w;
        }
        float* spb = sp + ks * 128 + hl * 8;
        #pragma unroll
        for (int s = 0; s < 8; ++s) spb[s] = acc[s];
        __syncthreads();
        if (tid < 128) {            // tid = hl2*8 + s
            float a = 0.f;
            #pragma unroll
            for (int u = 0; u < 16; ++u) a += sp[u * 128 + tid];
            const int hl2 = tid >> 3, s = tid & 7;
            ws[WS_QKV + proc * 2304 + mat * 768 + s * 96 + six * 16 + hl2] = a;
        }
    } else if (blk < 176) {
        for (int k = tid; k < 512; k += 256) sK[k] = x[k];
        __syncthreads();
        const int ml = tid & 15, ks = tid >> 4;        // ks 0..15, 32 k each
        const int m = (blk - 144) * 16 + ml;
        const float* W = Wa + (ks * 32) * 512 + m;
        const float* xq = sK + ks * 32;
        float acc = 0.f;
        #pragma unroll
        for (int k = 0; k < 32; ++k) acc += xq[k] * W[k * 512];
        sp[tid] = acc;
        __syncthreads();
        if (tid < 16) {
            float a = ba[(blk - 144) * 16 + tid];
            #pragma unroll
            for (int u = 0; u < 16; ++u) a += sp[u * 16 + tid];
            ws[WS_ALPHA + (blk - 144) * 16 + tid] = 1.f / (1.f + __expf(-a));
        }
    } else {
        for (int k = tid; k < 512; k += 256) sK[k] = x[k];
        __syncthreads();
        const int hl = tid & 31, ks = tid >> 5;        // ks 0..7, 64 k each
        const int h = (blk - 176) * 32 + hl;           // 3*32 = 96
        const float* W = Wqr + (ks * 64) * 96 + h;
        const float* xq = sK + ks * 64;
        float acc = 0.f;
        #pragma unroll
        for (int k = 0; k < 64; ++k) acc += xq[k] * W[k * 96];
        sp[tid] = acc;
        __syncthreads();
        if (ks == 0) {
            float a = bqr[h];
            #pragma unroll
            for (int u = 0; u < 8; ++u) a += sp[hl + 32 * u];
            ws[WS_Q + h] = fmaxf(a, 0.f);
        }
    }
}

// ---------------------------------------------------------------------------
// KB (48 x 256): (proc, mat, third). Each block redundantly computes attn1
// (from ws QKV1, no weights) and full H2 = H + relu(H@fc1) (36KB fc1), then
// its 256-output slice of K2/V2 (12KB). Weights/block = 48KB.
// ---------------------------------------------------------------------------
__global__ __launch_bounds__(256) void kB_attn1_fc1_kv2(
    const float* __restrict__ fc1w, const float* __restrict__ Wk2,
    const float* __restrict__ Wv2, float* __restrict__ ws)
{
    const int b = blockIdx.x, proc = b / 6, rem = b % 6;
    const int mat = rem / 3, t = rem % 3, tid = threadIdx.x;
    __shared__ float sQk[768], sKk[768], sVv[768], sH[768], sH2[768], sS[192];
    const float rs = 0.10206207261596577f;  // 1/sqrt(96)

    const float* qkv = ws + WS_QKV + proc * 2304;
    for (int i = tid; i < 768; i += 256) {
        sQk[i] = qkv[i]; sKk[i] = qkv[768 + i]; sVv[i] = qkv[1536 + i];
    }
    __syncthreads();
    if (tid < 192) {       // attn1 logits: (h0, si, sk)
        const int h0 = tid / 64, r64 = tid % 64, si = r64 / 8, sk = r64 % 8;
        float acc = 0.f;
        #pragma unroll
        for (int d = 0; d < 32; ++d)
            acc += sQk[si * 96 + h0 * 32 + d] * sKk[sk * 96 + h0 * 32 + d];
        sS[tid] = acc * rs;
    }
    __syncthreads();
    if (tid < 24) {        // softmax row -> normalized probs in place
        float* row = sS + tid * 8;
        float mx = row[0];
        #pragma unroll
        for (int k = 1; k < 8; ++k) mx = fmaxf(mx, row[k]);
        float e[8], sum = 0.f;
        #pragma unroll
        for (int k = 0; k < 8; ++k) { e[k] = __expf(row[k] - mx); sum += e[k]; }
        const float inv = 1.f / sum;
        #pragma unroll
        for (int k = 0; k < 8; ++k) row[k] = e[k] * inv;
    }
    __syncthreads();
    if (tid < 192) {       // AV + residual: (h0, si, dq) -> 4 d's each
        const int h0 = tid / 64, r64 = tid % 64, si = r64 / 8, dq = r64 % 8;
        const float* e = sS + h0 * 64 + si * 8;
        float o0 = 0.f, o1 = 0.f, o2 = 0.f, o3 = 0.f;
        #pragma unroll
        for (int k = 0; k < 8; ++k) {
            const float ek = e[k];
            const float* v = sVv + k * 96 + h0 * 32 + dq * 4;
            o0 += ek * v[0]; o1 += ek * v[1]; o2 += ek * v[2]; o3 += ek * v[3];
        }
        const int base = si * 96 + h0 * 32 + dq * 4;
        sH[base + 0] = sQk[base + 0] + o0;
        sH[base + 1] = sQk[base + 1] + o1;
        sH[base + 2] = sQk[base + 2] + o2;
        sH[base + 3] = sQk[base + 3] + o3;
    }
    __syncthreads();
    // fc1 (full, redundant): 3 outputs/thread
    #pragma unroll
    for (int r = 0; r < 3; ++r) {
        const int idx = tid + 256 * r, s = idx / 96, j = idx % 96;
        const float* W = fc1w + proc * 9216 + j;
        const float* Hs = sH + s * 96;
        float acc = 0.f;
        #pragma unroll
        for (int i = 0; i < 96; ++i) acc += Hs[i] * W[i * 96];
        sH2[idx] = sH[idx] + fmaxf(acc, 0.f);
    }
    __syncthreads();
    // K2/V2 slice: (s, jl) -> j = t*32+jl
    const int s = tid >> 5, jl = tid & 31, j = t * 32 + jl;
    const float* W = (mat ? Wv2 : Wk2) + proc * 9216 + j;
    const float* Hs = sH2 + s * 96;
    float acc = 0.f;
    #pragma unroll
    for (int i = 0; i < 96; ++i) acc += Hs[i] * W[i * 96];
    ws[(mat ? WS_V2 : WS_K2) + proc * 768 + s * 96 + j] = acc;
}

// ---------------------------------------------------------------------------
// KC (64 x 256): (proc, eighth). Each block redundantly computes Qq = q@Wq2
// (36KB), attn2 (no weights), Of = O + relu(O@fc2) (36KB), then its 64-map
// Wo slice (24KB) + epilogue. Weights/block = 96KB.
// ---------------------------------------------------------------------------
__global__ __launch_bounds__(256) void kC_qq_attn2_fc2_out(
    const float* __restrict__ gate, const float* __restrict__ De,
    const float* __restrict__ regs, const float* __restrict__ Wq2,
    const float* __restrict__ fc2w, const float* __restrict__ Wo,
    const float* __restrict__ ws, float* __restrict__ out)
{
    const int b = blockIdx.x, proc = b >> 3, e = b & 7, tid = threadIdx.x;
    __shared__ float sK2[768], sV2[768];
    __shared__ float sq[96], sQq[96], sO[96], sOf[96], sE2[128], sg[8], sp[256];
    const float rs = 0.10206207261596577f;

    for (int i = tid; i < 768; i += 256) {
        sK2[i] = ws[WS_K2 + proc * 768 + i];
        sV2[i] = ws[WS_V2 + proc * 768 + i];
    }
    if (tid < 96) sq[tid] = ws[WS_Q + tid];
    else if (tid >= 96 && tid < 104) sg[tid - 96] = gate[tid - 96];
    __syncthreads();

    // Qq = q @ Wq2 (2-way k-split over 192 threads)
    if (tid < 192) {
        const int j = tid % 96, ks = tid / 96;
        const float* W = Wq2 + proc * 9216 + j + (ks * 48) * 96;
        const float* xq = sq + ks * 48;
        float acc = 0.f;
        #pragma unroll
        for (int i = 0; i < 48; ++i) acc += xq[i] * W[i * 96];
        sp[tid] = acc;
    }
    __syncthreads();
    if (tid < 96) sQq[tid] = sp[tid] + sp[96 + tid];
    __syncthreads();

    // attn2 probs: 16 heads, d=6, 1 query row
    if (tid < 16) {
        const int h0 = tid;
        float lg[8], mx = -1e30f;
        #pragma unroll
        for (int k = 0; k < 8; ++k) {
            float acc = 0.f;
            #pragma unroll
            for (int d = 0; d < 6; ++d)
                acc += sQq[h0 * 6 + d] * sK2[k * 96 + h0 * 6 + d];
            lg[k] = acc * rs; mx = fmaxf(mx, lg[k]);
        }
        float ex[8], sum = 0.f;
        #pragma unroll
        for (int k = 0; k < 8; ++k) { ex[k] = __expf(lg[k] - mx); sum += ex[k]; }
        const float inv = 1.f / sum;
        #pragma unroll
        for (int k = 0; k < 8; ++k) sE2[h0 * 8 + k] = ex[k] * inv;
    }
    __syncthreads();
    // AV + residual: tid<96 = (h0, d)
    if (tid < 96) {
        const int h0 = tid / 6;
        float o = 0.f;
        #pragma unroll
        for (int k = 0; k < 8; ++k) o += sE2[h0 * 8 + k] * sV2[k * 96 + tid];
        sO[tid] = sQq[tid] + o;
    }
    __syncthreads();
    // fc2 (2-way k-split)
    if (tid < 192) {
        const int j = tid % 96, ks = tid / 96;
        const float* W = fc2w + proc * 9216 + j + (ks * 48) * 96;
        const float* Os = sO + ks * 48;
        float acc = 0.f;
        #pragma unroll
        for (int i = 0; i < 48; ++i) acc += Os[i] * W[i * 96];
        sp[tid] = acc;
    }
    __syncthreads();
    if (tid < 96) sOf[tid] = sO[tid] + fmaxf(sp[tid] + sp[96 + tid], 0.f);
    __syncthreads();

    // Wo slice: 64 maps, 4-way k-split
    const int ml = tid & 63, ks = tid >> 6;
    const int m = 64 * e + ml;
    const float* W = Wo + proc * 49152 + m;
    float acc = 0.f;
    #pragma unroll
    for (int i = 0; i < 24; ++i)
        acc += sOf[24 * ks + i] * W[(24 * ks + i) * 512];
    sp[tid] = acc;
    __syncthreads();
    if (ks == 0) {
        const float tr = sp[ml] + sp[ml + 64] + sp[ml + 128] + sp[ml + 192];
        const float4* Dp4 = (const float4*)(De + proc * 4096 + m * 8);
        const float4 d0 = Dp4[0], d1 = Dp4[1];
        const float de = d0.x * sg[0] + d0.y * sg[1] + d0.z * sg[2] + d0.w * sg[3]
                       + d1.x * sg[4] + d1.y * sg[5] + d1.z * sg[6] + d1.w * sg[7];
        const float a = ws[WS_ALPHA + m];
        const float mix = a * tr + (1.f - a) * de;
        const int pt = proc & 3;                 // gamma gets +1, beta not
        const float off = (pt == 0 || pt == 2) ? 1.f : 0.f;
        out[proc * 512 + m] = mix * regs[proc * 512 + m] + off;
    }
}

extern "C" void kernel_launch(void* const* d_in, const int* in_sizes, int n_in,
                              void* d_out, int out_size, void* d_ws, size_t ws_size,
                              hipStream_t stream)
{
    const float* gate = (const float*)d_in[0];
    const float* x    = (const float*)d_in[1];
    const float* Wa   = (const float*)d_in[2];
    const float* ba   = (const float*)d_in[3];
    const float* Wqr  = (const float*)d_in[4];
    const float* bqr  = (const float*)d_in[5];
    const float* P    = (const float*)d_in[6];
    const float* De   = (const float*)d_in[7];
    const float* regs = (const float*)d_in[8];
    const float* Wq1  = (const float*)d_in[9];
    const float* Wk1  = (const float*)d_in[10];
    const float* Wv1  = (const float*)d_in[11];
    const float* fc1  = (const float*)d_in[12];
    const float* Wq2  = (const float*)d_in[13];
    const float* Wk2  = (const float*)d_in[14];
    const float* Wv2  = (const float*)d_in[15];
    const float* fc2  = (const float*)d_in[16];
    const float* Wo   = (const float*)d_in[17];
    float* ws = (float*)d_ws;

    hipLaunchKernelGGL(kA_qkv_alpha_q, dim3(179), dim3(256), 0, stream,
                       x, Wa, ba, Wqr, bqr, P, Wq1, Wk1, Wv1, ws);
    hipLaunchKernelGGL(kB_attn1_fc1_kv2, dim3(48), dim3(256), 0, stream,
                       fc1, Wk2, Wv2, ws);
    hipLaunchKernelGGL(kC_qq_attn2_fc2_out, dim3(64), dim3(256), 0, stream,
                       gate, De, regs, Wq2, fc2, Wo, ws, (float*)d_out);
}

// Round 7
// 108.971 us; speedup vs baseline: 1.4683x; 1.0074x over previous
//
#include <hip/hip_runtime.h>
#include <hip/hip_bf16.h>
#include <math.h>

// NUM_MAPS=512, ZG=512, HID=96, SEQ=8, H1=3, H2=16, NPROC=8. fp32 in/out.
// R6 ledger: fixed harness ~84us; controllable ~26us over 3 kernels. Each
// kernel pays ~4-5 exposed cold-HBM rounds (weights fetched at phase start,
// 1 blk/CU = nothing hides them) + 2 launch gaps. R7: burst-prefetch phase
// weights into LDS at kernel entry (coalesced float4, each byte once —
// unlike R4's global re-read prime), move Qq to kB, hoist kA weight loads
// into regs before the staging sync.

#define WS_ALPHA 0
#define WS_Q     512
#define WS_QKV   608      // 8*2304 -> 19040
#define WS_K2    19040    // 8*768  -> 25184
#define WS_V2    25184    // 8*768  -> 31328
#define WS_QQ    31328    // 8*96   -> 32096

// ---------------------------------------------------------------------------
// KA (182 x 256):
//  blk 0..143   : QKV1. (proc, mat, sixth): 16 h x 8 s outs; thread (hl16,
//                 ks16): 32 W loads hoisted to regs, K tile skewed in LDS.
//  blk 144..175 : alpha. 16 m/blk, 16-way k-split, W hoisted.
//  blk 176..181 : q. 16 h/blk, 16-way k-split, W hoisted.
// ---------------------------------------------------------------------------
__global__ __launch_bounds__(256) void kA_qkv_alpha_q(
    const float* __restrict__ x, const float* __restrict__ Wa,
    const float* __restrict__ ba, const float* __restrict__ Wqr,
    const float* __restrict__ bqr, const float* __restrict__ P,
    const float* __restrict__ Wq1, const float* __restrict__ Wk1,
    const float* __restrict__ Wv1, float* __restrict__ ws)
{
    __shared__ float sK[8 * 528];   // skewed K tile (c -> c + c/32), or x
    __shared__ float sp[2048];      // partial sums
    const int blk = blockIdx.x, tid = threadIdx.x;

    if (blk < 144) {
        const int proc = blk / 18, rem = blk % 18, mat = rem / 6, six = rem % 6;
        const int hl = tid & 15, ks = tid >> 4;        // ks 0..15
        const int h = six * 16 + hl;
        const float* W = (mat == 0 ? Wq1 : (mat == 1 ? Wk1 : Wv1))
                         + proc * 49152 + (ks * 32) * 96 + h;
        float wreg[32];
        #pragma unroll
        for (int m2 = 0; m2 < 32; ++m2) wreg[m2] = W[m2 * 96];  // issued early
        // stage K[s][c] = P[proc,c,s], column skewed c -> c + (c>>5)
        const float4* P4 = (const float4*)(P + proc * 4096);
        for (int i = tid; i < 1024; i += 256) {
            float4 v = P4[i];
            const int c = i >> 1, off = (i & 1) * 4;
            const int cp = c + (c >> 5);
            sK[(off + 0) * 528 + cp] = v.x;
            sK[(off + 1) * 528 + cp] = v.y;
            sK[(off + 2) * 528 + cp] = v.z;
            sK[(off + 3) * 528 + cp] = v.w;
        }
        __syncthreads();
        const float* Kb = sK + ks * 33;                // skewed base
        float acc[8] = {0.f,0.f,0.f,0.f,0.f,0.f,0.f,0.f};
        #pragma unroll
        for (int m2 = 0; m2 < 32; ++m2) {
            const float w = wreg[m2];
            const float* Kc = Kb + m2;
            #pragma unroll
            for (int s = 0; s < 8; ++s) acc[s] += Kc[s * 528] * w;
        }
        float* spb = sp + ks * 128 + hl * 8;
        #pragma unroll
        for (int s = 0; s < 8; ++s) spb[s] = acc[s];
        __syncthreads();
        if (tid < 128) {            // tid = hl2*8 + s
            float a = 0.f;
            #pragma unroll
            for (int u = 0; u < 16; ++u) a += sp[u * 128 + tid];
            const int hl2 = tid >> 3, s = tid & 7;
            ws[WS_QKV + proc * 2304 + mat * 768 + s * 96 + six * 16 + hl2] = a;
        }
    } else if (blk < 176) {
        const int ml = tid & 15, ks = tid >> 4;        // 32 k each
        const int m = (blk - 144) * 16 + ml;
        const float* W = Wa + (ks * 32) * 512 + m;
        float wreg[32];
        #pragma unroll
        for (int k = 0; k < 32; ++k) wreg[k] = W[k * 512];
        for (int k = tid; k < 512; k += 256) sK[k] = x[k];
        __syncthreads();
        const float* xq = sK + ks * 32;
        float acc = 0.f;
        #pragma unroll
        for (int k = 0; k < 32; ++k) acc += xq[k] * wreg[k];
        sp[tid] = acc;
        __syncthreads();
        if (tid < 16) {
            float a = ba[(blk - 144) * 16 + tid];
            #pragma unroll
            for (int u = 0; u < 16; ++u) a += sp[u * 16 + tid];
            ws[WS_ALPHA + (blk - 144) * 16 + tid] = 1.f / (1.f + __expf(-a));
        }
    } else {
        const int hl = tid & 15, ks = tid >> 4;        // 32 k each
        const int h = (blk - 176) * 16 + hl;           // 6*16 = 96
        const float* W = Wqr + (ks * 32) * 96 + h;
        float wreg[32];
        #pragma unroll
        for (int k = 0; k < 32; ++k) wreg[k] = W[k * 96];
        for (int k = tid; k < 512; k += 256) sK[k] = x[k];
        __syncthreads();
        const float* xq = sK + ks * 32;
        float acc = 0.f;
        #pragma unroll
        for (int k = 0; k < 32; ++k) acc += xq[k] * wreg[k];
        sp[tid] = acc;
        __syncthreads();
        if (tid < 16) {
            float a = bqr[(blk - 176) * 16 + tid];
            #pragma unroll
            for (int u = 0; u < 16; ++u) a += sp[u * 16 + tid];
            ws[WS_Q + (blk - 176) * 16 + tid] = fmaxf(a, 0.f);
        }
    }
}

// ---------------------------------------------------------------------------
// KB (72 x 256): blk<48: (proc, mat, third) — entry burst-stages fc1 (36KB)
// + Wk2/Wv2 slice (12KB) into LDS, then attn1 -> fc1 -> K2/V2 slice.
// blk 48..71: Qq = q @ Wq2 (proc, third), 8-way k-split (R5-verified).
// ---------------------------------------------------------------------------
__global__ __launch_bounds__(256) void kB_attn1_fc1_kv2(
    const float* __restrict__ fc1w, const float* __restrict__ Wk2,
    const float* __restrict__ Wv2, const float* __restrict__ Wq2,
    float* __restrict__ ws)
{
    const int b = blockIdx.x, tid = threadIdx.x;
    const float rs = 0.10206207261596577f;  // 1/sqrt(96)

    if (b < 48) {
        const int proc = b / 6, rem = b % 6, mat = rem / 3, t = rem % 3;
        __shared__ float sQk[768], sKk[768], sVv[768], sH[768], sH2[768], sS[192];
        __shared__ float sWf1[9216];     // fc1, row-major [i][j]
        __shared__ float sWkv[96 * 32];  // Wk2/Wv2 column slice [i][jl]

        // ---- entry burst: all weight bytes, coalesced float4, once ----
        {
            const float4* F4 = (const float4*)fc1w + proc * 2304;
            float4* D4 = (float4*)sWf1;
            #pragma unroll
            for (int r = 0; r < 9; ++r) D4[tid + 256 * r] = F4[tid + 256 * r];
            const float4* KV4 = (const float4*)(mat ? Wv2 : Wk2);
            float4* E4 = (float4*)sWkv;
            #pragma unroll
            for (int r = 0; r < 3; ++r) {
                const int idx = tid + 256 * r;          // 768 float4
                const int row = idx >> 3, q4 = idx & 7;
                E4[row * 8 + q4] = KV4[proc * 2304 + row * 24 + t * 8 + q4];
            }
        }
        const float* qkv = ws + WS_QKV + proc * 2304;
        for (int i = tid; i < 768; i += 256) {
            sQk[i] = qkv[i]; sKk[i] = qkv[768 + i]; sVv[i] = qkv[1536 + i];
        }
        __syncthreads();

        if (tid < 192) {       // attn1 logits (h0, si, sk)
            const int h0 = tid / 64, r64 = tid % 64, si = r64 / 8, sk = r64 % 8;
            float acc = 0.f;
            #pragma unroll
            for (int d = 0; d < 32; ++d)
                acc += sQk[si * 96 + h0 * 32 + d] * sKk[sk * 96 + h0 * 32 + d];
            sS[tid] = acc * rs;
        }
        __syncthreads();
        if (tid < 24) {        // softmax row -> probs in place
            float* row = sS + tid * 8;
            float mx = row[0];
            #pragma unroll
            for (int k = 1; k < 8; ++k) mx = fmaxf(mx, row[k]);
            float e[8], sum = 0.f;
            #pragma unroll
            for (int k = 0; k < 8; ++k) { e[k] = __expf(row[k] - mx); sum += e[k]; }
            const float inv = 1.f / sum;
            #pragma unroll
            for (int k = 0; k < 8; ++k) row[k] = e[k] * inv;
        }
        __syncthreads();
        if (tid < 192) {       // AV + residual (h0, si, dq): 4 d's each
            const int h0 = tid / 64, r64 = tid % 64, si = r64 / 8, dq = r64 % 8;
            const float* e = sS + h0 * 64 + si * 8;
            float o0 = 0.f, o1 = 0.f, o2 = 0.f, o3 = 0.f;
            #pragma unroll
            for (int k = 0; k < 8; ++k) {
                const float ek = e[k];
                const float* v = sVv + k * 96 + h0 * 32 + dq * 4;
                o0 += ek*v[0]; o1 += ek*v[1]; o2 += ek*v[2]; o3 += ek*v[3];
            }
            const int base = si * 96 + h0 * 32 + dq * 4;
            sH[base+0] = sQk[base+0] + o0;  sH[base+1] = sQk[base+1] + o1;
            sH[base+2] = sQk[base+2] + o2;  sH[base+3] = sQk[base+3] + o3;
        }
        __syncthreads();
        // fc1 from LDS (full, redundant): 3 outputs/thread
        #pragma unroll
        for (int r = 0; r < 3; ++r) {
            const int idx = tid + 256 * r, s = idx / 96, j = idx % 96;
            const float* Hs = sH + s * 96;
            float acc = 0.f;
            #pragma unroll
            for (int i = 0; i < 96; ++i) acc += Hs[i] * sWf1[i * 96 + j];
            sH2[idx] = sH[idx] + fmaxf(acc, 0.f);
        }
        __syncthreads();
        // K2/V2 slice from LDS: (s, jl)
        const int s = tid >> 5, jl = tid & 31, j = t * 32 + jl;
        const float* Hs = sH2 + s * 96;
        float acc = 0.f;
        #pragma unroll
        for (int i = 0; i < 96; ++i) acc += Hs[i] * sWkv[i * 32 + jl];
        ws[(mat ? WS_V2 : WS_K2) + proc * 768 + s * 96 + j] = acc;
    } else {
        const int b2 = b - 48, proc = b2 / 3, t = b2 % 3;
        __shared__ float sq[96], sp[256];
        if (tid < 96) sq[tid] = ws[WS_Q + tid];
        __syncthreads();
        const int jl = tid & 31, ks = tid >> 5;
        const int j = 32 * t + jl;
        const float* W = Wq2 + proc * 9216 + j;
        float acc = 0.f;
        #pragma unroll
        for (int i = 0; i < 12; ++i)
            acc += sq[12 * ks + i] * W[(12 * ks + i) * 96];
        sp[tid] = acc;
        __syncthreads();
        if (ks == 0) {
            float a = 0.f;
            #pragma unroll
            for (int u = 0; u < 8; ++u) a += sp[jl + 32 * u];
            ws[WS_QQ + proc * 96 + j] = a;
        }
    }
}

// ---------------------------------------------------------------------------
// KC (64 x 256): (proc, eighth). Entry burst-stages fc2 (36KB) + Wo slice
// (24KB) into LDS + K2/V2/Qq from ws + De/alpha/regs into regs. Then attn2,
// fc2 (LDS), Wo slice (LDS) + epilogue.
// ---------------------------------------------------------------------------
__global__ __launch_bounds__(256) void kC_attn2_fc2_out(
    const float* __restrict__ gate, const float* __restrict__ De,
    const float* __restrict__ regs, const float* __restrict__ fc2w,
    const float* __restrict__ Wo, const float* __restrict__ ws,
    float* __restrict__ out)
{
    const int b = blockIdx.x, proc = b >> 3, e = b & 7, tid = threadIdx.x;
    __shared__ float sK2[768], sV2[768];
    __shared__ float sQq[96], sO[96], sOf[96], sE2[128], sg[8], sp[256];
    __shared__ float sWf2[9216];     // fc2 [i][j]
    __shared__ float sWo[96 * 64];   // Wo slice [h][ml]
    const float rs = 0.10206207261596577f;

    // ---- entry burst ----
    {
        const float4* F4 = (const float4*)fc2w + proc * 2304;
        float4* D4 = (float4*)sWf2;
        #pragma unroll
        for (int r = 0; r < 9; ++r) D4[tid + 256 * r] = F4[tid + 256 * r];
        const float4* W4 = (const float4*)Wo;
        float4* E4 = (float4*)sWo;
        #pragma unroll
        for (int r = 0; r < 6; ++r) {
            const int idx = tid + 256 * r;              // 1536 float4
            const int row = idx >> 4, q4 = idx & 15;
            E4[row * 16 + q4] = W4[proc * 12288 + row * 128 + e * 16 + q4];
        }
    }
    const int ml = tid & 63, ks = tid >> 6;
    const int m = 64 * e + ml;
    // epilogue operands prefetched into regs (redundant across ks, cheap)
    const float4* Dp4 = (const float4*)(De + proc * 4096 + m * 8);
    const float4 d0 = Dp4[0], d1 = Dp4[1];
    const float av = ws[WS_ALPHA + m];
    const float rg = regs[proc * 512 + m];
    for (int i = tid; i < 768; i += 256) {
        sK2[i] = ws[WS_K2 + proc * 768 + i];
        sV2[i] = ws[WS_V2 + proc * 768 + i];
    }
    if (tid < 96) sQq[tid] = ws[WS_QQ + proc * 96 + tid];
    else if (tid >= 96 && tid < 104) sg[tid - 96] = gate[tid - 96];
    __syncthreads();

    // attn2 probs: 16 heads, d=6, 1 query row
    if (tid < 16) {
        const int h0 = tid;
        float lg[8], mx = -1e30f;
        #pragma unroll
        for (int k = 0; k < 8; ++k) {
            float acc = 0.f;
            #pragma unroll
            for (int d = 0; d < 6; ++d)
                acc += sQq[h0 * 6 + d] * sK2[k * 96 + h0 * 6 + d];
            lg[k] = acc * rs; mx = fmaxf(mx, lg[k]);
        }
        float ex[8], sum = 0.f;
        #pragma unroll
        for (int k = 0; k < 8; ++k) { ex[k] = __expf(lg[k] - mx); sum += ex[k]; }
        const float inv = 1.f / sum;
        #pragma unroll
        for (int k = 0; k < 8; ++k) sE2[h0 * 8 + k] = ex[k] * inv;
    }
    __syncthreads();
    if (tid < 96) {           // AV + residual
        const int h0 = tid / 6;
        float o = 0.f;
        #pragma unroll
        for (int k = 0; k < 8; ++k) o += sE2[h0 * 8 + k] * sV2[k * 96 + tid];
        sO[tid] = sQq[tid] + o;
    }
    __syncthreads();
    if (tid < 192) {          // fc2 from LDS, 2-way k-split
        const int j = tid % 96, k2 = tid / 96;
        const float* Os = sO + k2 * 48;
        float acc = 0.f;
        #pragma unroll
        for (int i = 0; i < 48; ++i) acc += Os[i] * sWf2[(k2 * 48 + i) * 96 + j];
        sp[tid] = acc;
    }
    __syncthreads();
    if (tid < 96) sOf[tid] = sO[tid] + fmaxf(sp[tid] + sp[96 + tid], 0.f);
    __syncthreads();

    // Wo slice from LDS: 64 maps, 4-way k-split
    float acc = 0.f;
    #pragma unroll
    for (int i = 0; i < 24; ++i)
        acc += sOf[24 * ks + i] * sWo[(24 * ks + i) * 64 + ml];
    sp[tid] = acc;
    __syncthreads();
    if (ks == 0) {
        const float tr = sp[ml] + sp[ml + 64] + sp[ml + 128] + sp[ml + 192];
        const float de = d0.x * sg[0] + d0.y * sg[1] + d0.z * sg[2] + d0.w * sg[3]
                       + d1.x * sg[4] + d1.y * sg[5] + d1.z * sg[6] + d1.w * sg[7];
        const float mix = av * tr + (1.f - av) * de;
        const int pt = proc & 3;                 // gamma gets +1, beta not
        const float off = (pt == 0 || pt == 2) ? 1.f : 0.f;
        out[proc * 512 + m] = mix * rg + off;
    }
}

extern "C" void kernel_launch(void* const* d_in, const int* in_sizes, int n_in,
                              void* d_out, int out_size, void* d_ws, size_t ws_size,
                              hipStream_t stream)
{
    const float* gate = (const float*)d_in[0];
    const float* x    = (const float*)d_in[1];
    const float* Wa   = (const float*)d_in[2];
    const float* ba   = (const float*)d_in[3];
    const float* Wqr  = (const float*)d_in[4];
    const float* bqr  = (const float*)d_in[5];
    const float* P    = (const float*)d_in[6];
    const float* De   = (const float*)d_in[7];
    const float* regs = (const float*)d_in[8];
    const float* Wq1  = (const float*)d_in[9];
    const float* Wk1  = (const float*)d_in[10];
    const float* Wv1  = (const float*)d_in[11];
    const float* fc1  = (const float*)d_in[12];
    const float* Wq2  = (const float*)d_in[13];
    const float* Wk2  = (const float*)d_in[14];
    const float* Wv2  = (const float*)d_in[15];
    const float* fc2  = (const float*)d_in[16];
    const float* Wo   = (const float*)d_in[17];
    float* ws = (float*)d_ws;

    hipLaunchKernelGGL(kA_qkv_alpha_q, dim3(182), dim3(256), 0, stream,
                       x, Wa, ba, Wqr, bqr, P, Wq1, Wk1, Wv1, ws);
    hipLaunchKernelGGL(kB_attn1_fc1_kv2, dim3(72), dim3(256), 0, stream,
                       fc1, Wk2, Wv2, Wq2, ws);
    hipLaunchKernelGGL(kC_attn2_fc2_out, dim3(64), dim3(256), 0, stream,
                       gate, De, regs, fc2, Wo, ws, (float*)d_out);
}